// Round 12
// baseline (3793.114 us; speedup 1.0000x reference)
//
#include <hip/hip_runtime.h>
#include <hip/hip_bf16.h>
#include <cstdint>

#define HDIM 128

typedef __bf16 bf16x8 __attribute__((ext_vector_type(8)));
typedef unsigned short usx8 __attribute__((ext_vector_type(8)));
typedef float fx4 __attribute__((ext_vector_type(4)));

__device__ __forceinline__ float bf2f(unsigned short u) {
    unsigned int x = ((unsigned int)u) << 16;
    return __uint_as_float(x);
}
__device__ __forceinline__ unsigned short f2bf(float f) {
    unsigned int x = __float_as_uint(f);
    x += 0x7fffu + ((x >> 16) & 1u);
    return (unsigned short)(x >> 16);
}

__device__ __forceinline__ void detect_local(const unsigned int* xw, const unsigned int* eiw,
                                             int& f0, int& f1) {
    int sane = 0;
    for (int k = 0; k < 64; k++) {
        unsigned int w = xw[k];
        unsigned short ss[2] = {(unsigned short)(w & 0xffffu), (unsigned short)(w >> 16)};
        for (int q = 0; q < 2; q++) {
            int e = (ss[q] >> 7) & 0xFF;
            if ((ss[q] & 0x7fffu) == 0 || (e >= 100 && e <= 140)) sane++;
        }
    }
    f0 = (sane >= 110) ? 1 : 0;
    int zeros = 0;
    for (int k = 1; k < 64; k += 2)
        if (eiw[k] == 0) zeros++;
    f1 = (zeros >= 24) ? 1 : 0;
}

struct ParamTab {
    const void* p[15];
    int n[15];
    int off[15];
};

// ---------------- phase1: hist + param-convert + gbounds + repack + init ----------------
__global__ void phase1(const unsigned int* __restrict__ xw, const unsigned int* __restrict__ eiw,
                       const void* __restrict__ ei, const void* __restrict__ batch,
                       const void* __restrict__ W1, const void* __restrict__ W2,
                       const void* __restrict__ W3, ParamTab tab, int* __restrict__ flags,
                       float* __restrict__ gsumAll, int* __restrict__ Ct,
                       unsigned short* __restrict__ wconv, unsigned short* __restrict__ Wf,
                       int* __restrict__ goff, int* __restrict__ gcnt, int E, int N, int G,
                       int NB, int ntiles, int TILE) {
    __shared__ int h[1024];
    __shared__ int lf0s, lf1s;
    int b = blockIdx.x, t = threadIdx.x;
    if (t == 0) {
        int a0, a1;
        detect_local(xw, eiw, a0, a1);
        lf0s = a0;
        lf1s = a1;
    }
    __syncthreads();
    int lf0 = lf0s, lf1 = lf1s;
    if (b < ntiles) {
        for (int i = t; i < NB; i += 256) h[i] = 0;
        __syncthreads();
        int base = b * TILE;
        for (int i = t; i < TILE; i += 256) {
            int idx = base + i;
            if (idx < E) {
                int d = lf1 ? ((const int*)ei)[2 * ((size_t)E + idx)]
                            : ((const int*)ei)[(size_t)E + idx];
                atomicAdd(&h[d >> 9], 1);
            }
        }
        __syncthreads();
        for (int k = t; k < NB; k += 256) Ct[k * ntiles + b] = h[k];
    } else if (b < ntiles + 15) {
        int pb = b - ntiles;
        const void* src = tab.p[pb];
        int n = tab.n[pb];
        unsigned short* o = wconv + tab.off[pb];
        if (lf0) {
            const unsigned short* s = (const unsigned short*)src;
            for (int i = t; i < n; i += 256) o[i] = s[i];
        } else {
            const float* s = (const float*)src;
            for (int i = t; i < n; i += 256) o[i] = f2bf(s[i]);
        }
    } else if (b < ntiles + 17) {
        int gi = (b - ntiles - 15) * 256 + t;
        if (gi < G) {
            auto getb = [&](int i) -> int {
                return lf1 ? (int)((const long long*)batch)[i] : ((const int*)batch)[i];
            };
            auto lower = [&](int val) -> int {
                int lo = 0, hi = N;
                while (lo < hi) {
                    int mid = (lo + hi) >> 1;
                    if (getb(mid) < val) lo = mid + 1;
                    else hi = mid;
                }
                return lo;
            };
            int lo = lower(gi), hi = lower(gi + 1);
            goff[gi] = lo;
            gcnt[gi] = hi - lo;
        }
    } else if (b < ntiles + 41) {
        int idx = (b - ntiles - 17) * 256 + t;  // 0..6143
        int layer = idx >> 11;
        int rem = idx & 2047;
        int kt = rem >> 9, nt = (rem >> 6) & 7, lane = rem & 63;
        const void* W = (layer == 0) ? W1 : ((layer == 1) ? W2 : W3);
        int row = lane & 15, quad = lane >> 4;
        unsigned short* o =
            Wf + ((size_t)layer * 2048 + (size_t)((kt * 8 + nt) * 64 + lane)) * 8;
#pragma unroll
        for (int j = 0; j < 8; j++) {
            int k = kt * 32 + quad * 8 + j;
            int off = k * HDIM + nt * 16 + row;
            o[j] = lf0 ? ((const unsigned short*)W)[off] : f2bf(((const float*)W)[off]);
        }
    } else {
        for (int i = t; i < 8192; i += 256) gsumAll[i] = 0.f;
        if (t == 0) {
            flags[0] = lf0;
            flags[1] = lf1;
        }
    }
}

// ---------------- per-bucket scan over its tile counts (512 threads; ntiles<=512) ---------
__global__ void s1_scan(int* __restrict__ Ct, int* __restrict__ btot, int NB, int ntiles) {
    __shared__ int buf[512];
    int b = blockIdx.x, t = threadIdx.x;
    int v = (t < ntiles) ? Ct[b * ntiles + t] : 0;
    buf[t] = v;
    __syncthreads();
    for (int o = 1; o < 512; o <<= 1) {
        int a = (t >= o) ? buf[t - o] : 0;
        __syncthreads();
        buf[t] += a;
        __syncthreads();
    }
    if (t < ntiles) Ct[b * ntiles + t] = buf[t] - v;  // exclusive within bucket
    if (t == 0) btot[b] = buf[511];
}

// ---------------- scatter to bucket-contiguous packed pairs ----------------
__global__ void p1_scatter(const void* __restrict__ ei, const int* __restrict__ flags,
                           const int* __restrict__ Ct, const int* __restrict__ btot,
                           unsigned int* __restrict__ pairs, int E, int NB, int ntiles,
                           int TILE) {
    __shared__ int cur[1024];
    __shared__ int bb[256];
    int tile = blockIdx.x, t = threadIdx.x;
    int v = (t < NB) ? btot[t] : 0;
    bb[t] = v;
    __syncthreads();
    for (int o = 1; o < 256; o <<= 1) {
        int a = (t >= o) ? bb[t - o] : 0;
        __syncthreads();
        bb[t] += a;
        __syncthreads();
    }
    if (t < NB) cur[t] = (bb[t] - v) + Ct[t * ntiles + tile];
    __syncthreads();
    int base = tile * TILE;
    bool i64 = flags[1] != 0;
    for (int i = t; i < TILE; i += 256) {
        int idx = base + i;
        if (idx < E) {
            int s, d;
            if (i64) {
                s = ((const int*)ei)[2 * (size_t)idx];
                d = ((const int*)ei)[2 * ((size_t)E + idx)];
            } else {
                s = ((const int*)ei)[idx];
                d = ((const int*)ei)[(size_t)E + idx];
            }
            int pos = atomicAdd(&cur[d >> 9], 1);
            pairs[pos] = ((unsigned)(d & 511) << 23) | (unsigned)s;
        }
    }
}

// ---------------- per-bucket degree histogram -> dis ----------------
__global__ void p2_dis(const unsigned int* __restrict__ pairs, const int* __restrict__ btot,
                       float* __restrict__ dis, int N, int NB) {
    __shared__ int hist[512];
    __shared__ int bb[256];
    int b = blockIdx.x, t = threadIdx.x;
    int v = (t < NB) ? btot[t] : 0;
    bb[t] = v;
    __syncthreads();
    for (int o = 1; o < 256; o <<= 1) {
        int a = (t >= o) ? bb[t - o] : 0;
        __syncthreads();
        bb[t] += a;
        __syncthreads();
    }
    int lo = bb[b] - btot[b];
    int hi = lo + btot[b];
    for (int i = t; i < 512; i += 256) hist[i] = 0;
    __syncthreads();
    for (int i = lo + t; i < hi; i += 256) atomicAdd(&hist[pairs[i] >> 23], 1);
    __syncthreads();
    for (int i = t; i < 512; i += 256) {
        int node = b * 512 + i;
        if (node < N) dis[node] = rsqrtf((float)(hist[i] + 1));
    }
}

// ---------------- GEMM: hw[slice][m][16] = dis[m] * (bnrelu(A)[m,:] @ W), bf16 MFMA --------
__global__ __launch_bounds__(256) void mm_mfma(const void* __restrict__ A,
                                               const unsigned short* __restrict__ Wf,
                                               unsigned short* __restrict__ C, int M,
                                               const float* __restrict__ gsumPrev,
                                               const unsigned short* __restrict__ gamma,
                                               const unsigned short* __restrict__ beta,
                                               const float* __restrict__ dis,
                                               const int* __restrict__ flags, int l0mode,
                                               float invn) {
    __shared__ float scs[128], shs[128];
    __shared__ unsigned short ldsC[4 * 16 * 136];
    int t = threadIdx.x;
    if (!l0mode && t < 128) {
        float s = 0.f, s2 = 0.f;
#pragma unroll
        for (int r = 0; r < 8; r++) {
            s += gsumPrev[r * 256 + t];
            s2 += gsumPrev[r * 256 + 128 + t];
        }
        float m = s * invn;
        float vv = s2 * invn - m * m;
        float sc = bf2f(gamma[t]) * rsqrtf(vv + 1e-5f);
        scs[t] = sc;
        shs[t] = bf2f(beta[t]) - m * sc;
    }
    __syncthreads();
    int gid = blockIdx.x * blockDim.x + t;
    int wave = gid >> 6;
    int lane = t & 63;
    int wv = t >> 6;
    int m0 = wave * 16;
    if (m0 >= M) return;
    int row = lane & 15, quad = lane >> 4;
    bool xfp32 = l0mode && !flags[0];
    const unsigned short* arow = (const unsigned short*)A + (size_t)(m0 + row) * HDIM + quad * 8;
    const float* arowf = (const float*)A + (size_t)(m0 + row) * HDIM + quad * 8;
    fx4 acc[8];
#pragma unroll
    for (int k = 0; k < 8; k++) acc[k] = (fx4){0.f, 0.f, 0.f, 0.f};
#pragma unroll
    for (int kt = 0; kt < 4; kt++) {
        bf16x8 a;
        if (xfp32) {
            fx4 f0 = *(const fx4*)(arowf + kt * 32);
            fx4 f1 = *(const fx4*)(arowf + kt * 32 + 4);
            usx8 tt;
#pragma unroll
            for (int q = 0; q < 4; q++) tt[q] = f2bf(f0[q]);
#pragma unroll
            for (int q = 0; q < 4; q++) tt[4 + q] = f2bf(f1[q]);
            a = __builtin_bit_cast(bf16x8, tt);
        } else {
            usx8 raw = *(const usx8*)(arow + kt * 32);
            if (!l0mode) {
                int col = kt * 32 + quad * 8;
                fx4 s0 = *(const fx4*)&scs[col];
                fx4 s1 = *(const fx4*)&scs[col + 4];
                fx4 h0 = *(const fx4*)&shs[col];
                fx4 h1 = *(const fx4*)&shs[col + 4];
                usx8 tt;
#pragma unroll
                for (int q = 0; q < 4; q++)
                    tt[q] = f2bf(fmaxf(s0[q] * bf2f(raw[q]) + h0[q], 0.f));
#pragma unroll
                for (int q = 0; q < 4; q++)
                    tt[4 + q] = f2bf(fmaxf(s1[q] * bf2f(raw[4 + q]) + h1[q], 0.f));
                a = __builtin_bit_cast(bf16x8, tt);
            } else {
                a = __builtin_bit_cast(bf16x8, raw);
            }
        }
        const unsigned short* wf = Wf + ((size_t)(kt * 8) * 64 + lane) * 8;
#pragma unroll
        for (int nt = 0; nt < 8; nt++) {
            bf16x8 bfr = __builtin_bit_cast(bf16x8, *(const usx8*)(wf + (size_t)nt * 64 * 8));
            acc[nt] = __builtin_amdgcn_mfma_f32_16x16x32_bf16(a, bfr, acc[nt], 0, 0, 0);
        }
    }
    float dsc[4];
#pragma unroll
    for (int r = 0; r < 4; r++) dsc[r] = dis[m0 + quad * 4 + r];
    unsigned short* lw = ldsC + wv * 16 * 136;
#pragma unroll
    for (int nt = 0; nt < 8; nt++) {
        int col = nt * 16 + row;
#pragma unroll
        for (int r = 0; r < 4; r++) {
            lw[(quad * 4 + r) * 136 + col] = f2bf(acc[nt][r] * dsc[r]);
        }
    }
    int row16 = lane & 15;
    int sgrp = lane >> 4;
#pragma unroll
    for (int k = 0; k < 2; k++) {
        int s = sgrp * 2 + k;
        const unsigned short* src = lw + row16 * 136 + s * 16;
        unsigned short* dst = C + (size_t)s * M * 16 + (size_t)(m0 + row16) * 16;
        *(usx8*)(dst) = *(const usx8*)(src);
        *(usx8*)(dst + 8) = *(const usx8*)(src + 8);
    }
}

// ---------------- aggregation: edge-parallel per (bucket,slice), LDS accumulator ----------
__global__ __launch_bounds__(256, 4) void aggregate(const unsigned short* __restrict__ hw,
                                                    const float* __restrict__ dis,
                                                    const unsigned int* __restrict__ pairs,
                                                    const int* __restrict__ btot,
                                                    const unsigned short* __restrict__ bias,
                                                    unsigned short* __restrict__ agg,
                                                    float* __restrict__ gsum8, int n, int NB) {
    __shared__ float acc[512 * 17];  // padded rows: bank = (ld*17+off)%32 spreads
    __shared__ int bb[256];
    __shared__ float partials[32 * 8];
    int t = threadIdx.x;
    int slice = blockIdx.x & 7;
    int bkt = blockIdx.x >> 3;
    int node0 = bkt * 512;
    const unsigned short* hws = hw + (size_t)slice * n * 16;
    // bucket range via LDS scan of btot
    int v = (t < NB) ? btot[t] : 0;
    bb[t] = v;
    __syncthreads();
    for (int o = 1; o < 256; o <<= 1) {
        int a = (t >= o) ? bb[t - o] : 0;
        __syncthreads();
        bb[t] += a;
        __syncthreads();
    }
    int lo = bb[bkt] - btot[bkt];
    int hi = lo + btot[bkt];
    // init acc with self rows (coalesced 16B/thread)
    for (int i = t; i < 1024; i += 256) {
        int row = i >> 1, h = i & 1;
        int node = node0 + row;
        if (node < n) {
            usx8 sv = *(const usx8*)(hws + (size_t)node * 16 + h * 8);
#pragma unroll
            for (int q = 0; q < 8; q++) acc[row * 17 + h * 8 + q] = bf2f(sv[q]);
        }
    }
    __syncthreads();
    // edge loop: 2 lanes per edge, 16B gather each, LDS atomic accumulate
    int h = t & 1;
    for (int i = lo + (t >> 1); i < hi; i += 128) {
        unsigned int p = pairs[i];
        int ld = p >> 23;
        int src = (int)(p & 0x7fffffu);
        usx8 vv = *(const usx8*)(hws + (size_t)src * 16 + h * 8);
#pragma unroll
        for (int q = 0; q < 8; q++) atomicAdd(&acc[ld * 17 + h * 8 + q], bf2f(vv[q]));
    }
    __syncthreads();
    // finalize: 2 rows per thread (t, t+256), write agg + gather stats
    float bvals[16];
#pragma unroll
    for (int q = 0; q < 16; q++) bvals[q] = bf2f(bias[slice * 16 + q]);
    float sum[16], sq[16];
#pragma unroll
    for (int q = 0; q < 16; q++) {
        sum[q] = 0.f;
        sq[q] = 0.f;
    }
    for (int r = 0; r < 2; r++) {
        int row = t + 256 * r;
        int node = node0 + row;
        if (node >= n) continue;
        float di = dis[node];
        usx8 o0, o1;
#pragma unroll
        for (int q = 0; q < 8; q++) {
            float val = bvals[q] + di * acc[row * 17 + q];
            o0[q] = f2bf(val);
            float vr = bf2f(o0[q]);
            sum[q] += vr;
            sq[q] += vr * vr;
        }
#pragma unroll
        for (int q = 0; q < 8; q++) {
            float val = bvals[8 + q] + di * acc[row * 17 + 8 + q];
            o1[q] = f2bf(val);
            float vr = bf2f(o1[q]);
            sum[8 + q] += vr;
            sq[8 + q] += vr * vr;
        }
        unsigned short* dst = agg + (size_t)node * HDIM + slice * 16;
        *(usx8*)dst = o0;
        *(usx8*)(dst + 8) = o1;
    }
    __syncthreads();
    // stats reduce: dump 32 values/thread as [k][t], two-stage
#pragma unroll
    for (int q = 0; q < 16; q++) {
        acc[q * 256 + t] = sum[q];
        acc[(16 + q) * 256 + t] = sq[q];
    }
    __syncthreads();
    if (t < 256) {
        int k = t >> 3;   // 0..31
        int p = t & 7;    // 8 partials per k
        float s = 0.f;
        const float* base = &acc[k * 256 + p * 32];
        for (int j = 0; j < 32; j++) s += base[j];
        partials[k * 8 + p] = s;
    }
    __syncthreads();
    if (t < 32) {
        float s = 0.f;
#pragma unroll
        for (int p = 0; p < 8; p++) s += partials[t * 8 + p];
        int isq = t >> 4;
        int q = t & 15;
        atomicAdd(&gsum8[(bkt & 7) * 256 + isq * 128 + slice * 16 + q], s);
    }
}

// ---------------- pooling (computes BN3 in-block, fused ReLU) + pooled-stat atomics -------
__global__ void pool(const unsigned short* __restrict__ hin, const int* __restrict__ goff,
                     const int* __restrict__ gcnt, const float* __restrict__ gsum3,
                     const unsigned short* __restrict__ gamma,
                     const unsigned short* __restrict__ beta, float* __restrict__ pooled,
                     float* __restrict__ psum8, float invn) {
    __shared__ float scs[128], shs[128];
    __shared__ float ls[256];
    int g = blockIdx.x, t = threadIdx.x;
    if (t < 128) {
        float s = 0.f, s2 = 0.f;
#pragma unroll
        for (int r = 0; r < 8; r++) {
            s += gsum3[r * 256 + t];
            s2 += gsum3[r * 256 + 128 + t];
        }
        float m = s * invn;
        float vv = s2 * invn - m * m;
        float sc = bf2f(gamma[t]) * rsqrtf(vv + 1e-5f);
        scs[t] = sc;
        shs[t] = bf2f(beta[t]) - m * sc;
    }
    __syncthreads();
    int c = t & 127, p = t >> 7;
    float scale = scs[c], shift = shs[c];
    int s = goff[g], cn = gcnt[g];
    float acc = 0.f;
    for (int r = s + p; r < s + cn; r += 2)
        acc += fmaxf(scale * bf2f(hin[(size_t)r * HDIM + c]) + shift, 0.f);
    ls[t] = acc;
    __syncthreads();
    if (t < 128) {
        float pv = (ls[t] + ls[t + 128]) / fmaxf((float)cn, 1.f);
        pooled[(size_t)g * HDIM + t] = pv;
        int rep = (g & 7) * 256;
        atomicAdd(&psum8[rep + t], pv);
        atomicAdd(&psum8[rep + 128 + t], pv * pv);
    }
}

// ---------------- pooled-BN (from replicas) + MLP head + log_softmax ----------------
__global__ void mlp12(const float* __restrict__ pooled, const float* __restrict__ psum8,
                      const unsigned short* __restrict__ gp,
                      const unsigned short* __restrict__ bep,
                      const unsigned short* __restrict__ lw1,
                      const unsigned short* __restrict__ lb1,
                      const unsigned short* __restrict__ lw2,
                      const unsigned short* __restrict__ lb2, void* __restrict__ out,
                      const int* __restrict__ flags, int G_) {
    int r = blockIdx.x, t = threadIdx.x;
    __shared__ float row[128];
    __shared__ float z1s[128];
    __shared__ float z2[10];
    __shared__ float lse;
    float s = 0.f, s2 = 0.f;
#pragma unroll
    for (int k = 0; k < 8; k++) {
        s += psum8[k * 256 + t];
        s2 += psum8[k * 256 + 128 + t];
    }
    float m = s / (float)G_;
    float vv = s2 / (float)G_ - m * m;
    float psc = bf2f(gp[t]) * rsqrtf(vv + 1e-5f);
    float psh = bf2f(bep[t]) - m * psc;
    row[t] = psc * pooled[(size_t)r * HDIM + t] + psh;
    __syncthreads();
    float acc = bf2f(lb1[t]);
    for (int k = 0; k < 128; k++) acc += row[k] * bf2f(lw1[k * HDIM + t]);
    z1s[t] = fmaxf(acc, 0.f);
    __syncthreads();
    if (t < 10) {
        float a = bf2f(lb2[t]);
        for (int k = 0; k < 128; k++) a += z1s[k] * bf2f(lw2[k * 10 + t]);
        z2[t] = a;
    }
    __syncthreads();
    if (t == 0) {
        float mm = z2[0];
        for (int j = 1; j < 10; j++) mm = fmaxf(mm, z2[j]);
        float ss = 0.f;
        for (int j = 0; j < 10; j++) ss += expf(z2[j] - mm);
        lse = mm + logf(ss);
    }
    __syncthreads();
    if (t < 10) {
        float v = z2[t] - lse;
        if (flags[0]) ((unsigned short*)out)[r * 10 + t] = f2bf(v);
        else ((float*)out)[r * 10 + t] = v;
    }
}

extern "C" void kernel_launch(void* const* d_in, const int* in_sizes, int n_in,
                              void* d_out, int out_size, void* d_ws, size_t ws_size,
                              hipStream_t stream) {
    const void* x = d_in[0];
    const void* ei = d_in[1];
    const void* batch = d_in[2];

    int N_ = in_sizes[2];
    int E_ = in_sizes[1] / 2;
    int G_ = out_size / 10;

    const int TILE = 4096;      // ntiles <= 512 required by s1_scan
    int NB = (N_ + 511) / 512;  // <= 256 required by in-kernel base scans
    int ntiles = (E_ + TILE - 1) / TILE;
    int L = NB * ntiles;

    char* ws = (char*)d_ws;
    auto alloc = [&](size_t bytes) -> char* {
        char* p = ws;
        ws += (bytes + 255) & ~(size_t)255;
        return p;
    };
    int* flags = (int*)alloc(256);
    float* dis = (float*)alloc((size_t)N_ * 4);
    int* Ct = (int*)alloc((size_t)L * 4);
    int* btot = (int*)alloc(1024);
    unsigned int* pairs = (unsigned int*)alloc((size_t)E_ * 4);
    unsigned short* hw = (unsigned short*)alloc((size_t)N_ * HDIM * 2);      // column-blocked
    unsigned short* aggbuf = (unsigned short*)alloc((size_t)N_ * HDIM * 2);  // row-major
    unsigned short* wconv = (unsigned short*)alloc(70000 * 2);
    unsigned short* wfrag = (unsigned short*)alloc(3 * HDIM * HDIM * 2);
    float* gsumAll = (float*)alloc(8192 * 4);  // 3 layers x 2048 + psum 2048
    int* gcnt = (int*)alloc((size_t)G_ * 4);
    int* goff = (int*)alloc((size_t)G_ * 4);
    float* pooled = (float*)alloc((size_t)G_ * HDIM * 4);

    const int oB = 49152;
    const int oLB1 = oB + 1408;
    const int oLW1 = oLB1 + 128;
    const int oLW2 = oLW1 + 16384;
    const int oLB2 = oLW2 + 1280;

    ParamTab tab;
    const int srcIdx[15] = {4, 5, 6, 8, 9, 10, 12, 13, 14, 15, 16, 18, 17, 19, 20};
    const int dstOff[15] = {oB + 0, oB + 128, oB + 256,
                            oB + 384, oB + 512, oB + 640,
                            oB + 768, oB + 896, oB + 1024,
                            oB + 1152, oB + 1280,
                            oLB1, oLW1, oLW2, oLB2};
    for (int i = 0; i < 15; i++) {
        tab.p[i] = d_in[srcIdx[i]];
        tab.n[i] = in_sizes[srcIdx[i]];
        tab.off[i] = dstOff[i];
    }

    int p1_grid = ntiles + 15 + 2 + 24 + 1;
    phase1<<<p1_grid, 256, 0, stream>>>((const unsigned int*)x, (const unsigned int*)ei, ei,
                                        batch, d_in[3], d_in[7], d_in[11], tab, flags, gsumAll,
                                        Ct, wconv, wfrag, goff, gcnt, E_, N_, G_, NB, ntiles,
                                        TILE);
    s1_scan<<<NB, 512, 0, stream>>>(Ct, btot, NB, ntiles);
    p1_scatter<<<ntiles, 256, 0, stream>>>(ei, flags, Ct, btot, pairs, E_, NB, ntiles, TILE);
    p2_dis<<<NB, 256, 0, stream>>>(pairs, btot, dis, N_, NB);

    int mm_blocks = (((N_ + 15) / 16) * 64 + 255) / 256;
    float invn = 1.f / (float)N_;

    for (int l = 0; l < 3; l++) {
        const void* A = (l == 0) ? x : (const void*)aggbuf;
        const float* gp = (l == 0) ? nullptr : (gsumAll + (size_t)(l - 1) * 2048);
        const unsigned short* gam = wconv + oB + (l ? (l - 1) * 384 + 128 : 0);
        const unsigned short* bet = wconv + oB + (l ? (l - 1) * 384 + 256 : 0);
        mm_mfma<<<mm_blocks, 256, 0, stream>>>(A, wfrag + (size_t)l * HDIM * HDIM, hw, N_, gp,
                                               gam, bet, dis, flags, (l == 0) ? 1 : 0, invn);
        aggregate<<<NB * 8, 256, 0, stream>>>(hw, dis, pairs, btot, wconv + oB + l * 384,
                                              aggbuf, gsumAll + (size_t)l * 2048, N_, NB);
    }

    pool<<<G_, 256, 0, stream>>>(aggbuf, goff, gcnt, gsumAll + 2 * 2048,
                                 wconv + oB + 2 * 384 + 128, wconv + oB + 2 * 384 + 256, pooled,
                                 gsumAll + 3 * 2048, invn);
    mlp12<<<G_, 128, 0, stream>>>(pooled, gsumAll + 3 * 2048, wconv + oB + 1152,
                                  wconv + oB + 1280, wconv + oLW1, wconv + oLB1, wconv + oLW2,
                                  wconv + oLB2, d_out, flags, G_);
}